// Round 15
// baseline (196.579 us; speedup 1.0000x reference)
//
#include <hip/hip_runtime.h>
#include <hip/hip_fp16.h>
#include <hip/hip_cooperative_groups.h>

namespace cg = cooperative_groups;

#define NN 50000
#define NE 800000
#define NG 64
#define DF 96
#define SLOPE 0.2f
#define NBK 196   // (NN+255)/256 buckets of 256 dst nodes
#define EB 196    // (NE+4095)/4096 edge blocks (4096 edges per block)

using half8 = __attribute__((ext_vector_type(8))) _Float16;
using f32x4 = __attribute__((ext_vector_type(4))) float;

// ================= cooperative fused CSR build =================
// 196 blocks x 256. Phases: hist -> colscan(+gstart,+zero partial) -> bin -> per-bucket CSR.
__global__ __launch_bounds__(256) void k_build(const int* __restrict__ src,
                                               const int* __restrict__ dst,
                                               const int* __restrict__ batch,
                                               int* __restrict__ hist2d,
                                               int* __restrict__ colpref,
                                               int* __restrict__ coltotal,
                                               int* __restrict__ gstart,
                                               int* __restrict__ binned,
                                               float* __restrict__ dinv,
                                               int* __restrict__ row_start,
                                               unsigned short* __restrict__ csr_src,
                                               float* __restrict__ partial) {
  cg::grid_group grid = cg::this_grid();
  __shared__ int h[256], cur[256], tmp[256];
  __shared__ int loff[NBK], gb[NBK];
  __shared__ int stage[4096];
  __shared__ unsigned char sbk[4096];
  int t = threadIdx.x;
  int blk = blockIdx.x;

  // ---- phase 1: per-block bucket histogram ----
  if (t < NBK) h[t] = 0;
  __syncthreads();
  int base = blk * 4096;
  for (int k = 0; k < 16; ++k) {
    int e = base + k * 256 + t;
    if (e < NE) atomicAdd(&h[dst[e] >> 8], 1);
  }
  __syncthreads();
  if (t < NBK) hist2d[blk * NBK + t] = h[t];
  grid.sync();

  // ---- phase 2: column scan (block = column); block0: gstart; block1: zero partial ----
  {
    int col = blk;
    int v = (t < EB) ? hist2d[t * NBK + col] : 0;
    tmp[t] = v;
    __syncthreads();
    for (int o = 1; o < 256; o <<= 1) {
      int u = (t >= o) ? tmp[t - o] : 0;
      __syncthreads();
      tmp[t] += u;
      __syncthreads();
    }
    if (t < EB) colpref[t * NBK + col] = tmp[t] - v;
    if (t == 255) coltotal[col] = tmp[t];
    if (blk == 0 && t <= NG) {  // graph bounds (batch sorted)
      int g = t, lo = 0, hi = NN;
      while (lo < hi) {
        int mid = (lo + hi) >> 1;
        if (batch[mid] < g) lo = mid + 1; else hi = mid;
      }
      gstart[g] = lo;
    }
    if (blk == 1)
      for (int i = t; i < NG * DF; i += 256) partial[i] = 0.f;
  }
  grid.sync();

  // ---- phase 3: bin edges (h[] still holds this block's bucket hist from phase 1) ----
  {
    int ctv = (t < NBK) ? coltotal[t] : 0;
    tmp[t] = ctv;
    __syncthreads();
    for (int o = 1; o < 256; o <<= 1) {
      int u = (t >= o) ? tmp[t - o] : 0;
      __syncthreads();
      tmp[t] += u;
      __syncthreads();
    }
    int bbase_t = tmp[t] - ctv;  // exclusive bucket base
    __syncthreads();
    tmp[t] = (t < NBK) ? h[t] : 0;
    __syncthreads();
    for (int o = 1; o < 256; o <<= 1) {
      int u = (t >= o) ? tmp[t - o] : 0;
      __syncthreads();
      tmp[t] += u;
      __syncthreads();
    }
    if (t < NBK) {
      int excl = tmp[t] - h[t];
      loff[t] = excl;
      cur[t] = excl;
      gb[t] = bbase_t + colpref[blk * NBK + t];
    }
    __syncthreads();
    for (int k = 0; k < 16; ++k) {
      int e = base + k * 256 + t;
      if (e < NE) {
        int d = dst[e];
        int b = d >> 8;
        int p = atomicAdd(&cur[b], 1);
        stage[p] = src[e] | ((d & 255) << 16);
        sbk[p] = (unsigned char)b;
      }
    }
    __syncthreads();
    int tot = min(4096, NE - base);
    for (int i = t; i < tot; i += 256) {
      int b = sbk[i];
      binned[gb[b] + (i - loff[b])] = stage[i];
    }
  }
  grid.sync();

  // ---- phase 4: per-bucket CSR build (block = bucket) ----
  {
    int ctv = (t < NBK) ? coltotal[t] : 0;
    h[t] = ctv;
    tmp[t] = ctv;
    __syncthreads();
    for (int o = 1; o < 256; o <<= 1) {
      int u = (t >= o) ? tmp[t - o] : 0;
      __syncthreads();
      tmp[t] += u;
      __syncthreads();
    }
    int ebeg = tmp[blk] - h[blk];
    int eend = tmp[blk];
    __syncthreads();
    h[t] = 0;
    __syncthreads();
    for (int i = ebeg + t; i < eend; i += 256) atomicAdd(&h[(unsigned)binned[i] >> 16], 1);
    __syncthreads();
    tmp[t] = h[t];
    __syncthreads();
    for (int o = 1; o < 256; o <<= 1) {
      int v = (t >= o) ? tmp[t - o] : 0;
      __syncthreads();
      tmp[t] += v;
      __syncthreads();
    }
    int excl = tmp[t] - h[t];
    int rs = ebeg + excl;
    cur[t] = rs;
    int n = blk * 256 + t;
    if (n < NN) {
      row_start[n] = rs;
      dinv[n] = rsqrtf((float)h[t] + 1.0f);
    }
    if (blk == NBK - 1 && t == 255) row_start[NN] = NE;
    __syncthreads();
    for (int i = ebeg + t; i < eend; i += 256) {
      int pr = binned[i];
      int p = atomicAdd(&cur[(unsigned)pr >> 16], 1);
      csr_src[p] = (unsigned short)(pr & 0xFFFF);
    }
  }
}

// ---------------- MFMA GEMM: G(fp16) = (X @ W) * dinv[row]; X fp32 or fp16 ----------------
#define WTP 104  // Wt row pad (halfs): 208B rows, 16B-aligned
template <typename T>
__global__ __launch_bounds__(256) void k_gemm(const T* __restrict__ X,
                                              const float* __restrict__ W,
                                              const float* __restrict__ dinv,
                                              __half* __restrict__ G) {
  __shared__ alignas(16) _Float16 Wt[DF * WTP];  // 19.5 KB, transposed W
  int t = threadIdx.x;
  for (int i = t; i < DF * DF; i += 256) {
    int k = i / DF, c = i % DF;
    Wt[c * WTP + k] = (_Float16)W[i];
  }
  __syncthreads();

  int wave = t >> 6;
  int lane = t & 63;
  int lrow = lane & 15;
  int kgrp = lane >> 4;
  int rowbase = blockIdx.x * 64 + wave * 16;
  int arow = min(rowbase + lrow, NN - 1);

  half8 a[3];
#pragma unroll
  for (int kt = 0; kt < 3; ++kt) {
    int k0 = kt * 32 + kgrp * 8;
    if constexpr (sizeof(T) == 4) {
      const float4* xp = (const float4*)((const float*)X + (size_t)arow * DF + k0);
      float4 v0 = xp[0], v1 = xp[1];
      a[kt][0] = (_Float16)v0.x; a[kt][1] = (_Float16)v0.y;
      a[kt][2] = (_Float16)v0.z; a[kt][3] = (_Float16)v0.w;
      a[kt][4] = (_Float16)v1.x; a[kt][5] = (_Float16)v1.y;
      a[kt][6] = (_Float16)v1.z; a[kt][7] = (_Float16)v1.w;
    } else {
      a[kt] = *(const half8*)((const _Float16*)X + (size_t)arow * DF + k0);
    }
  }

  float dvv[4];
  int orow0 = rowbase + kgrp * 4;
#pragma unroll
  for (int r = 0; r < 4; ++r)
    dvv[r] = (orow0 + r < NN) ? dinv[orow0 + r] : 0.f;

#pragma unroll
  for (int ct = 0; ct < 6; ++ct) {
    int colbase = ct * 16;
    f32x4 acc = {0.f, 0.f, 0.f, 0.f};
#pragma unroll
    for (int kt = 0; kt < 3; ++kt) {
      half8 b = *(const half8*)&Wt[(colbase + lrow) * WTP + kt * 32 + kgrp * 8];
      acc = __builtin_amdgcn_mfma_f32_16x16x32_f16(a[kt], b, acc, 0, 0, 0);
    }
#pragma unroll
    for (int r = 0; r < 4; ++r) {
      int orow = orow0 + r;
      if (orow < NN)
        G[(size_t)orow * DF + colbase + lrow] = __float2half(acc[r] * dvv[r]);
    }
  }
}

// ---------------- gather-aggregate: 16 lanes/node, fp16 in ----------------
// FINAL=0: write H (fp16).  FINAL=1: LDS-reduce block's 16 nodes -> per-graph partial atomics.
template <int FINAL>
__global__ __launch_bounds__(256) void k_agg(const __half* __restrict__ G,
                                             const float* __restrict__ dinv,
                                             const float* __restrict__ bias,
                                             const int* __restrict__ row_start,
                                             const unsigned short* __restrict__ csr_src,
                                             __half* __restrict__ H,
                                             const int* __restrict__ batch,
                                             float* __restrict__ partial) {
  int lane = threadIdx.x & 15;
  int grp = threadIdx.x >> 4;
  int n = blockIdx.x * 16 + grp;  // NN = 16*3125 exact
  const unsigned* rn = (const unsigned*)(G + (size_t)n * DF);
  unsigned su0 = rn[lane], su1 = rn[lane + 16], su2 = rn[lane + 32];
  float2 f0 = __half22float2(*(__half2*)&su0);
  float2 f1 = __half22float2(*(__half2*)&su1);
  float2 f2 = __half22float2(*(__half2*)&su2);
  float a00 = f0.x, a01 = f0.y, a10 = f1.x, a11 = f1.y, a20 = f2.x, a21 = f2.y;

  int s = row_start[n], e = row_start[n + 1];
  for (int j0 = s; j0 < e; j0 += 16) {
    int my = (j0 + lane < e) ? (int)csr_src[j0 + lane] : 0;
    int cnt = min(16, e - j0);
    int jj = 0;
    for (; jj + 8 <= cnt; jj += 8) {
      unsigned u[8][3];
#pragma unroll
      for (int q = 0; q < 8; ++q) {
        int srcn = __shfl(my, jj + q, 16);
        const unsigned* r2 = (const unsigned*)(G + (size_t)srcn * DF);
        u[q][0] = r2[lane];
        u[q][1] = r2[lane + 16];
        u[q][2] = r2[lane + 32];
      }
#pragma unroll
      for (int q = 0; q < 8; ++q) {
        float2 g0 = __half22float2(*(__half2*)&u[q][0]);
        float2 g1 = __half22float2(*(__half2*)&u[q][1]);
        float2 g2 = __half22float2(*(__half2*)&u[q][2]);
        a00 += g0.x; a01 += g0.y;
        a10 += g1.x; a11 += g1.y;
        a20 += g2.x; a21 += g2.y;
      }
    }
    for (; jj < cnt; ++jj) {
      int srcn = __shfl(my, jj, 16);
      const unsigned* r2 = (const unsigned*)(G + (size_t)srcn * DF);
      unsigned v0 = r2[lane], v1 = r2[lane + 16], v2 = r2[lane + 32];
      float2 g0 = __half22float2(*(__half2*)&v0);
      float2 g1 = __half22float2(*(__half2*)&v1);
      float2 g2 = __half22float2(*(__half2*)&v2);
      a00 += g0.x; a01 += g0.y;
      a10 += g1.x; a11 += g1.y;
      a20 += g2.x; a21 += g2.y;
    }
  }
  float dv = dinv[n];
  float2 b0 = *(const float2*)(bias + 2 * lane);
  float2 b1 = *(const float2*)(bias + 2 * lane + 32);
  float2 b2 = *(const float2*)(bias + 2 * lane + 64);
  float v00 = dv * a00 + b0.x, v01 = dv * a01 + b0.y;
  float v10 = dv * a10 + b1.x, v11 = dv * a11 + b1.y;
  float v20 = dv * a20 + b2.x, v21 = dv * a21 + b2.y;
  v00 = v00 > 0.f ? v00 : SLOPE * v00;
  v01 = v01 > 0.f ? v01 : SLOPE * v01;
  v10 = v10 > 0.f ? v10 : SLOPE * v10;
  v11 = v11 > 0.f ? v11 : SLOPE * v11;
  v20 = v20 > 0.f ? v20 : SLOPE * v20;
  v21 = v21 > 0.f ? v21 : SLOPE * v21;

  if (!FINAL) {
    __half2* hp = (__half2*)(H + (size_t)n * DF);
    hp[lane] = __floats2half2_rn(v00, v01);
    hp[lane + 16] = __floats2half2_rn(v10, v11);
    hp[lane + 32] = __floats2half2_rn(v20, v21);
  } else {
    __shared__ float red[16][DF];  // 6 KB
    __shared__ int gnode[16];
    red[grp][2 * lane] = v00;
    red[grp][2 * lane + 1] = v01;
    red[grp][32 + 2 * lane] = v10;
    red[grp][33 + 2 * lane] = v11;
    red[grp][64 + 2 * lane] = v20;
    red[grp][65 + 2 * lane] = v21;
    if (lane == 0) gnode[grp] = batch[n];
    __syncthreads();
    int f = threadIdx.x;
    if (f < DF) {
      int g0 = gnode[0], g15 = gnode[15];
      if (g0 == g15) {
        float sum = 0.f;
#pragma unroll
        for (int q = 0; q < 16; ++q) sum += red[q][f];
        atomicAdd(&partial[g0 * DF + f], sum);
      } else {
        for (int g = g0; g <= g15; ++g) {
          float sum = 0.f;
          bool any = false;
          for (int q = 0; q < 16; ++q)
            if (gnode[q] == g) { sum += red[q][f]; any = true; }
          if (any) atomicAdd(&partial[g * DF + f], sum);
        }
      }
    }
  }
}

// ---------------- final: mean + classifier ----------------
__global__ __launch_bounds__(128) void k_pool3(const float* __restrict__ partial,
                                               const int* __restrict__ gstart,
                                               const float* __restrict__ Wc,
                                               const float* __restrict__ bc,
                                               float* __restrict__ out) {
  __shared__ float pm[DF];
  int g = blockIdx.x;
  int t = threadIdx.x;
  if (t < DF) {
    float cnt = (float)(gstart[g + 1] - gstart[g]);
    pm[t] = partial[g * DF + t] / fmaxf(cnt, 1.0f);
  }
  __syncthreads();
  if (t < 2) {
    float s = 0.f;
    for (int c = 0; c < DF; ++c) s += pm[c] * Wc[c * 2 + t];
    out[g * 2 + t] = s + bc[t];
  }
}

extern "C" void kernel_launch(void* const* d_in, const int* in_sizes, int n_in,
                              void* d_out, int out_size, void* d_ws, size_t ws_size,
                              hipStream_t stream) {
  const float* x = (const float*)d_in[0];
  const int* ei = (const int*)d_in[1];
  const int* batch = (const int*)d_in[2];
  const float* W1 = (const float*)d_in[3];
  const float* b1 = (const float*)d_in[4];
  const float* W2 = (const float*)d_in[5];
  const float* b2 = (const float*)d_in[6];
  const float* Wc = (const float*)d_in[7];
  const float* bc = (const float*)d_in[8];
  float* out = (float*)d_out;
  const int* srcv = ei;
  const int* dstv = ei + NE;

  char* p = (char*)d_ws;
  auto alloc = [&](size_t bytes) {
    char* r = p;
    p += (bytes + 255) & ~(size_t)255;
    return r;
  };
  int* hist2d = (int*)alloc((size_t)EB * NBK * sizeof(int));
  int* colpref = (int*)alloc((size_t)EB * NBK * sizeof(int));
  int* coltotal = (int*)alloc((size_t)NBK * sizeof(int));
  int* gstart = (int*)alloc((size_t)(NG + 1) * sizeof(int));
  int* row_start = (int*)alloc((size_t)(NN + 1) * sizeof(int));
  int* binned = (int*)alloc((size_t)NE * sizeof(int));
  unsigned short* csr_src = (unsigned short*)alloc((size_t)NE * sizeof(unsigned short));
  float* dinv = (float*)alloc((size_t)NN * sizeof(float));
  __half* g = (__half*)alloc((size_t)NN * DF * sizeof(__half));
  __half* h = (__half*)alloc((size_t)NN * DF * sizeof(__half));
  float* partial = (float*)alloc((size_t)NG * DF * sizeof(float));

  void* bargs[] = {(void*)&srcv,     (void*)&dstv,    (void*)&batch,
                   (void*)&hist2d,   (void*)&colpref, (void*)&coltotal,
                   (void*)&gstart,   (void*)&binned,  (void*)&dinv,
                   (void*)&row_start,(void*)&csr_src, (void*)&partial};
  hipLaunchCooperativeKernel((const void*)k_build, dim3(NBK), dim3(256), bargs, 0, stream);

  const int GB = (NN + 63) / 64;  // 782 blocks, 64 rows each
  k_gemm<float><<<GB, 256, 0, stream>>>(x, W1, dinv, g);
  k_agg<0><<<NN / 16, 256, 0, stream>>>(g, dinv, b1, row_start, csr_src, h, batch, partial);
  k_gemm<__half><<<GB, 256, 0, stream>>>((const __half*)h, W2, dinv, g);
  k_agg<1><<<NN / 16, 256, 0, stream>>>(g, dinv, b2, row_start, csr_src, h, batch, partial);

  k_pool3<<<NG, 128, 0, stream>>>(partial, gstart, Wc, bc, out);
}

// Round 16
// 121.450 us; speedup vs baseline: 1.6186x; 1.6186x over previous
//
#include <hip/hip_runtime.h>
#include <hip/hip_fp16.h>

#define NN 50000
#define NE 800000
#define NG 64
#define DF 96
#define SLOPE 0.2f
#define NBK 196   // (NN+255)/256 buckets of 256 dst nodes
#define EB 196    // (NE+4095)/4096 edge blocks (4096 edges per block)

using half8 = __attribute__((ext_vector_type(8))) _Float16;
using f32x4 = __attribute__((ext_vector_type(4))) float;

// ---------------- pass A1: per-block bucket histogram (row-major out, coalesced) ----------------
__global__ __launch_bounds__(256) void k_hist(const int* __restrict__ dst,
                                              int* __restrict__ hist2d) {
  __shared__ int h[NBK];
  int t = threadIdx.x;
  if (t < NBK) h[t] = 0;
  __syncthreads();
  int base = blockIdx.x * 4096;
  for (int k = 0; k < 16; ++k) {
    int e = base + k * 256 + t;
    if (e < NE) atomicAdd(&h[dst[e] >> 8], 1);
  }
  __syncthreads();
  if (t < NBK) hist2d[blockIdx.x * NBK + t] = h[t];
}

// ---------------- per-column exclusive scan over edge-blocks; block 0 also graph bounds ----------
__global__ __launch_bounds__(256) void k_colscan(const int* __restrict__ hist2d,
                                                 int* __restrict__ colpref,
                                                 int* __restrict__ coltotal,
                                                 const int* __restrict__ batch,
                                                 int* __restrict__ gstart) {
  __shared__ int s[256];
  int col = blockIdx.x;
  int b = threadIdx.x;
  int v = (b < EB) ? hist2d[b * NBK + col] : 0;
  s[b] = v;
  __syncthreads();
  for (int o = 1; o < 256; o <<= 1) {
    int u = (b >= o) ? s[b - o] : 0;
    __syncthreads();
    s[b] += u;
    __syncthreads();
  }
  if (b < EB) colpref[b * NBK + col] = s[b] - v;
  if (b == 255) coltotal[col] = s[b];
  if (blockIdx.x == 0 && b <= NG) {
    int g = b, lo = 0, hi = NN;
    while (lo < hi) {
      int mid = (lo + hi) >> 1;
      if (batch[mid] < g) lo = mid + 1; else hi = mid;
    }
    gstart[g] = lo;
  }
}

// ---------------- pass A2: bin edges (deterministic offsets, LDS staged) ----------------
__global__ __launch_bounds__(256) void k_bin2(const int* __restrict__ src,
                                              const int* __restrict__ dst,
                                              const int* __restrict__ hist2d,
                                              const int* __restrict__ coltotal,
                                              const int* __restrict__ colpref,
                                              int* __restrict__ binned) {
  __shared__ int h[NBK], loff[NBK], cur[NBK], gb[NBK];
  __shared__ int tmp[256];
  __shared__ int stage[4096];
  __shared__ unsigned char sbk[4096];
  int t = threadIdx.x;
  int ctv = (t < NBK) ? coltotal[t] : 0;
  tmp[t] = ctv;
  __syncthreads();
  for (int o = 1; o < 256; o <<= 1) {
    int u = (t >= o) ? tmp[t - o] : 0;
    __syncthreads();
    tmp[t] += u;
    __syncthreads();
  }
  int bbase_t = tmp[t] - ctv;
  if (t < NBK) h[t] = hist2d[blockIdx.x * NBK + t];
  __syncthreads();
  tmp[t] = (t < NBK) ? h[t] : 0;
  __syncthreads();
  for (int o = 1; o < 256; o <<= 1) {
    int u = (t >= o) ? tmp[t - o] : 0;
    __syncthreads();
    tmp[t] += u;
    __syncthreads();
  }
  if (t < NBK) {
    int excl = tmp[t] - h[t];
    loff[t] = excl;
    cur[t] = excl;
    gb[t] = bbase_t + colpref[blockIdx.x * NBK + t];
  }
  __syncthreads();
  int base = blockIdx.x * 4096;
  for (int k = 0; k < 16; ++k) {
    int e = base + k * 256 + t;
    if (e < NE) {
      int d = dst[e];
      int b = d >> 8;
      int p = atomicAdd(&cur[b], 1);
      stage[p] = src[e] | ((d & 255) << 16);
      sbk[p] = (unsigned char)b;
    }
  }
  __syncthreads();
  int tot = min(4096, NE - base);
  for (int i = t; i < tot; i += 256) {
    int b = sbk[i];
    binned[gb[b] + (i - loff[b])] = stage[i];
  }
}

// ---------------- pass B: per-bucket CSR build + dinv/row_start; block 0 zeroes partial ----------
__global__ __launch_bounds__(256) void k_csr(const int* __restrict__ binned,
                                             const int* __restrict__ coltotal,
                                             float* __restrict__ dinv,
                                             int* __restrict__ row_start,
                                             unsigned short* __restrict__ csr_src,
                                             float* __restrict__ partial) {
  __shared__ int h[256], cur[256], tmp[256];
  int t = threadIdx.x;
  int b = blockIdx.x;
  if (b == 0)
    for (int i = t; i < NG * DF; i += 256) partial[i] = 0.f;
  int ctv = (t < NBK) ? coltotal[t] : 0;
  h[t] = ctv;
  tmp[t] = ctv;
  __syncthreads();
  for (int o = 1; o < 256; o <<= 1) {
    int u = (t >= o) ? tmp[t - o] : 0;
    __syncthreads();
    tmp[t] += u;
    __syncthreads();
  }
  int ebeg = tmp[b] - h[b];
  int eend = tmp[b];
  __syncthreads();
  h[t] = 0;
  __syncthreads();
  for (int i = ebeg + t; i < eend; i += 256) atomicAdd(&h[(unsigned)binned[i] >> 16], 1);
  __syncthreads();
  tmp[t] = h[t];
  __syncthreads();
  for (int o = 1; o < 256; o <<= 1) {
    int v = (t >= o) ? tmp[t - o] : 0;
    __syncthreads();
    tmp[t] += v;
    __syncthreads();
  }
  int excl = tmp[t] - h[t];
  int rs = ebeg + excl;
  cur[t] = rs;
  int n = b * 256 + t;
  if (n < NN) {
    row_start[n] = rs;
    dinv[n] = rsqrtf((float)h[t] + 1.0f);
  }
  if (b == NBK - 1 && t == 255) row_start[NN] = NE;
  __syncthreads();
  for (int i = ebeg + t; i < eend; i += 256) {
    int pr = binned[i];
    int p = atomicAdd(&cur[(unsigned)pr >> 16], 1);
    csr_src[p] = (unsigned short)(pr & 0xFFFF);
  }
}

// ---------------- MFMA GEMM: G(fp16) = (X @ W) * dinv[row]; X fp32 or fp16 ----------------
#define WTP 104  // Wt row pad (halfs): 208B rows, 16B-aligned
template <typename T>
__global__ __launch_bounds__(256) void k_gemm(const T* __restrict__ X,
                                              const float* __restrict__ W,
                                              const float* __restrict__ dinv,
                                              __half* __restrict__ G) {
  __shared__ alignas(16) _Float16 Wt[DF * WTP];  // 19.5 KB, transposed W
  int t = threadIdx.x;
  for (int i = t; i < DF * DF; i += 256) {
    int k = i / DF, c = i % DF;
    Wt[c * WTP + k] = (_Float16)W[i];
  }
  __syncthreads();

  int wave = t >> 6;
  int lane = t & 63;
  int lrow = lane & 15;
  int kgrp = lane >> 4;
  int rowbase = blockIdx.x * 64 + wave * 16;
  int arow = min(rowbase + lrow, NN - 1);

  half8 a[3];
#pragma unroll
  for (int kt = 0; kt < 3; ++kt) {
    int k0 = kt * 32 + kgrp * 8;
    if constexpr (sizeof(T) == 4) {
      const float4* xp = (const float4*)((const float*)X + (size_t)arow * DF + k0);
      float4 v0 = xp[0], v1 = xp[1];
      a[kt][0] = (_Float16)v0.x; a[kt][1] = (_Float16)v0.y;
      a[kt][2] = (_Float16)v0.z; a[kt][3] = (_Float16)v0.w;
      a[kt][4] = (_Float16)v1.x; a[kt][5] = (_Float16)v1.y;
      a[kt][6] = (_Float16)v1.z; a[kt][7] = (_Float16)v1.w;
    } else {
      a[kt] = *(const half8*)((const _Float16*)X + (size_t)arow * DF + k0);
    }
  }

  float dvv[4];
  int orow0 = rowbase + kgrp * 4;
#pragma unroll
  for (int r = 0; r < 4; ++r)
    dvv[r] = (orow0 + r < NN) ? dinv[orow0 + r] : 0.f;

#pragma unroll
  for (int ct = 0; ct < 6; ++ct) {
    int colbase = ct * 16;
    f32x4 acc = {0.f, 0.f, 0.f, 0.f};
#pragma unroll
    for (int kt = 0; kt < 3; ++kt) {
      half8 b = *(const half8*)&Wt[(colbase + lrow) * WTP + kt * 32 + kgrp * 8];
      acc = __builtin_amdgcn_mfma_f32_16x16x32_f16(a[kt], b, acc, 0, 0, 0);
    }
#pragma unroll
    for (int r = 0; r < 4; ++r) {
      int orow = orow0 + r;
      if (orow < NN)
        G[(size_t)orow * DF + colbase + lrow] = __float2half(acc[r] * dvv[r]);
    }
  }
}

// ---------------- gather-aggregate: 16 lanes/node, fp16 in ----------------
// FINAL=0: write H (fp16).  FINAL=1: LDS-reduce block's 16 nodes -> per-graph partial atomics.
template <int FINAL>
__global__ __launch_bounds__(256) void k_agg(const __half* __restrict__ G,
                                             const float* __restrict__ dinv,
                                             const float* __restrict__ bias,
                                             const int* __restrict__ row_start,
                                             const unsigned short* __restrict__ csr_src,
                                             __half* __restrict__ H,
                                             const int* __restrict__ batch,
                                             float* __restrict__ partial) {
  int lane = threadIdx.x & 15;
  int grp = threadIdx.x >> 4;
  int n = blockIdx.x * 16 + grp;  // NN = 16*3125 exact
  const unsigned* rn = (const unsigned*)(G + (size_t)n * DF);
  unsigned su0 = rn[lane], su1 = rn[lane + 16], su2 = rn[lane + 32];
  float2 f0 = __half22float2(*(__half2*)&su0);
  float2 f1 = __half22float2(*(__half2*)&su1);
  float2 f2 = __half22float2(*(__half2*)&su2);
  float a00 = f0.x, a01 = f0.y, a10 = f1.x, a11 = f1.y, a20 = f2.x, a21 = f2.y;

  int s = row_start[n], e = row_start[n + 1];
  for (int j0 = s; j0 < e; j0 += 16) {
    int my = (j0 + lane < e) ? (int)csr_src[j0 + lane] : 0;
    int cnt = min(16, e - j0);
    int jj = 0;
    for (; jj + 8 <= cnt; jj += 8) {
      unsigned u[8][3];
#pragma unroll
      for (int q = 0; q < 8; ++q) {
        int srcn = __shfl(my, jj + q, 16);
        const unsigned* r2 = (const unsigned*)(G + (size_t)srcn * DF);
        u[q][0] = r2[lane];
        u[q][1] = r2[lane + 16];
        u[q][2] = r2[lane + 32];
      }
#pragma unroll
      for (int q = 0; q < 8; ++q) {
        float2 g0 = __half22float2(*(__half2*)&u[q][0]);
        float2 g1 = __half22float2(*(__half2*)&u[q][1]);
        float2 g2 = __half22float2(*(__half2*)&u[q][2]);
        a00 += g0.x; a01 += g0.y;
        a10 += g1.x; a11 += g1.y;
        a20 += g2.x; a21 += g2.y;
      }
    }
    for (; jj < cnt; ++jj) {
      int srcn = __shfl(my, jj, 16);
      const unsigned* r2 = (const unsigned*)(G + (size_t)srcn * DF);
      unsigned v0 = r2[lane], v1 = r2[lane + 16], v2 = r2[lane + 32];
      float2 g0 = __half22float2(*(__half2*)&v0);
      float2 g1 = __half22float2(*(__half2*)&v1);
      float2 g2 = __half22float2(*(__half2*)&v2);
      a00 += g0.x; a01 += g0.y;
      a10 += g1.x; a11 += g1.y;
      a20 += g2.x; a21 += g2.y;
    }
  }
  float dv = dinv[n];
  float2 b0 = *(const float2*)(bias + 2 * lane);
  float2 b1 = *(const float2*)(bias + 2 * lane + 32);
  float2 b2 = *(const float2*)(bias + 2 * lane + 64);
  float v00 = dv * a00 + b0.x, v01 = dv * a01 + b0.y;
  float v10 = dv * a10 + b1.x, v11 = dv * a11 + b1.y;
  float v20 = dv * a20 + b2.x, v21 = dv * a21 + b2.y;
  v00 = v00 > 0.f ? v00 : SLOPE * v00;
  v01 = v01 > 0.f ? v01 : SLOPE * v01;
  v10 = v10 > 0.f ? v10 : SLOPE * v10;
  v11 = v11 > 0.f ? v11 : SLOPE * v11;
  v20 = v20 > 0.f ? v20 : SLOPE * v20;
  v21 = v21 > 0.f ? v21 : SLOPE * v21;

  if (!FINAL) {
    __half2* hp = (__half2*)(H + (size_t)n * DF);
    hp[lane] = __floats2half2_rn(v00, v01);
    hp[lane + 16] = __floats2half2_rn(v10, v11);
    hp[lane + 32] = __floats2half2_rn(v20, v21);
  } else {
    __shared__ float red[16][DF];  // 6 KB
    __shared__ int gnode[16];
    red[grp][2 * lane] = v00;
    red[grp][2 * lane + 1] = v01;
    red[grp][32 + 2 * lane] = v10;
    red[grp][33 + 2 * lane] = v11;
    red[grp][64 + 2 * lane] = v20;
    red[grp][65 + 2 * lane] = v21;
    if (lane == 0) gnode[grp] = batch[n];
    __syncthreads();
    int f = threadIdx.x;
    if (f < DF) {
      int g0 = gnode[0], g15 = gnode[15];
      if (g0 == g15) {
        float sum = 0.f;
#pragma unroll
        for (int q = 0; q < 16; ++q) sum += red[q][f];
        atomicAdd(&partial[g0 * DF + f], sum);
      } else {
        for (int g = g0; g <= g15; ++g) {
          float sum = 0.f;
          bool any = false;
          for (int q = 0; q < 16; ++q)
            if (gnode[q] == g) { sum += red[q][f]; any = true; }
          if (any) atomicAdd(&partial[g * DF + f], sum);
        }
      }
    }
  }
}

// ---------------- final: mean + classifier ----------------
__global__ __launch_bounds__(128) void k_pool3(const float* __restrict__ partial,
                                               const int* __restrict__ gstart,
                                               const float* __restrict__ Wc,
                                               const float* __restrict__ bc,
                                               float* __restrict__ out) {
  __shared__ float pm[DF];
  int g = blockIdx.x;
  int t = threadIdx.x;
  if (t < DF) {
    float cnt = (float)(gstart[g + 1] - gstart[g]);
    pm[t] = partial[g * DF + t] / fmaxf(cnt, 1.0f);
  }
  __syncthreads();
  if (t < 2) {
    float s = 0.f;
    for (int c = 0; c < DF; ++c) s += pm[c] * Wc[c * 2 + t];
    out[g * 2 + t] = s + bc[t];
  }
}

extern "C" void kernel_launch(void* const* d_in, const int* in_sizes, int n_in,
                              void* d_out, int out_size, void* d_ws, size_t ws_size,
                              hipStream_t stream) {
  const float* x = (const float*)d_in[0];
  const int* ei = (const int*)d_in[1];
  const int* batch = (const int*)d_in[2];
  const float* W1 = (const float*)d_in[3];
  const float* b1 = (const float*)d_in[4];
  const float* W2 = (const float*)d_in[5];
  const float* b2 = (const float*)d_in[6];
  const float* Wc = (const float*)d_in[7];
  const float* bc = (const float*)d_in[8];
  float* out = (float*)d_out;
  const int* srcv = ei;
  const int* dstv = ei + NE;

  char* p = (char*)d_ws;
  auto alloc = [&](size_t bytes) {
    char* r = p;
    p += (bytes + 255) & ~(size_t)255;
    return r;
  };
  int* hist2d = (int*)alloc((size_t)EB * NBK * sizeof(int));
  int* colpref = (int*)alloc((size_t)EB * NBK * sizeof(int));
  int* coltotal = (int*)alloc((size_t)NBK * sizeof(int));
  int* gstart = (int*)alloc((size_t)(NG + 1) * sizeof(int));
  int* row_start = (int*)alloc((size_t)(NN + 1) * sizeof(int));
  int* binned = (int*)alloc((size_t)NE * sizeof(int));
  unsigned short* csr_src = (unsigned short*)alloc((size_t)NE * sizeof(unsigned short));
  float* dinv = (float*)alloc((size_t)NN * sizeof(float));
  __half* g = (__half*)alloc((size_t)NN * DF * sizeof(__half));
  __half* h = (__half*)alloc((size_t)NN * DF * sizeof(__half));
  float* partial = (float*)alloc((size_t)NG * DF * sizeof(float));

  k_hist<<<EB, 256, 0, stream>>>(dstv, hist2d);
  k_colscan<<<NBK, 256, 0, stream>>>(hist2d, colpref, coltotal, batch, gstart);
  k_bin2<<<EB, 256, 0, stream>>>(srcv, dstv, hist2d, coltotal, colpref, binned);
  k_csr<<<NBK, 256, 0, stream>>>(binned, coltotal, dinv, row_start, csr_src, partial);

  const int GB = (NN + 63) / 64;  // 782 blocks, 64 rows each
  k_gemm<float><<<GB, 256, 0, stream>>>(x, W1, dinv, g);
  k_agg<0><<<NN / 16, 256, 0, stream>>>(g, dinv, b1, row_start, csr_src, h, batch, partial);
  k_gemm<__half><<<GB, 256, 0, stream>>>((const __half*)h, W2, dinv, g);
  k_agg<1><<<NN / 16, 256, 0, stream>>>(g, dinv, b2, row_start, csr_src, h, batch, partial);

  k_pool3<<<NG, 128, 0, stream>>>(partial, gstart, Wc, bc, out);
}